// Round 7
// baseline (204.695 us; speedup 1.0000x reference)
//
#include <hip/hip_runtime.h>

// Scaled dot-product attention, B=4 H=16 S=2048 D=64, fp32 in/out.
// R13: overlap exp-B under PV-A -- the R11 idea, restructured for register
// pressure (R11 spilled: vb hoisted before exp while all 64 s-regs live).
// Changes vs R12 (fa COMPUTE only, prep/pipeline/epilogue identical):
//   1. exp decomposed into EXPFRAG steps: one half8 A-fragment built
//      directly from 8 s-values (8 exp2 + 4 cvt_pkrtz), s-regs release
//      monotonically; no pk arrays, no pointer-to-local.
//   2. V fragments (vb[8], 32 regs) loaded BETWEEN exp-A frags 2 and 3:
//      s0A dies first (-16), vb arrives (+32), ds_read latency hides
//      under the remaining 2 exp-A frags. Peak live ~128-132 arch VGPRs.
//   3. exp-B frags threaded between PV-A MFMAs (VALU under matrix pipe);
//      PV-B reuses held vb -- LDS reads/tile unchanged (16 b128).
// Math bitwise-identical (same ops, same order per accumulator).
// Chain model: 512+290+max(330,290)+320 ~= 1450 cyc/tile vs ~1730 (R12).

#define S_LEN 2048
#define D_DIM 64
#define N_BH  64
#define QSCALE 0.18033688011112042f  // (1/sqrt(64)) * log2(e)

typedef _Float16 half8 __attribute__((ext_vector_type(8)));
typedef _Float16 half4 __attribute__((ext_vector_type(4)));
typedef float floatx16 __attribute__((ext_vector_type(16)));
typedef unsigned int uint4v __attribute__((ext_vector_type(4)));

#define MFMA32(a, b, c) __builtin_amdgcn_mfma_f32_32x32x16_f16((a), (b), (c), 0, 0, 0)

#define GLL16(g, l) __builtin_amdgcn_global_load_lds(                      \
    (const __attribute__((address_space(1))) void*)(g),                    \
    (__attribute__((address_space(3))) void*)(l), 16, 0, 0)

// ---- pre-pass: K fp32 -> f16 (same layout, streaming); V fp32 -> f16
// transposed to [bh][d][s'] where s' = s with bits 2<->3 swapped.
__global__ __launch_bounds__(256) void prep_kernel(
    const float* __restrict__ kg, const float* __restrict__ vg,
    _Float16* __restrict__ kh, _Float16* __restrict__ vt)
{
    __shared__ _Float16 Ls[64 * 132];
    const int tid = threadIdx.x;
    const int bh = blockIdx.y;
    const int sbase = blockIdx.x * 128;
    const size_t gbase = ((size_t)(bh * S_LEN + sbase)) * D_DIM;  // 8192 floats

#pragma unroll
    for (int i = 0; i < 8; ++i) {
        const int e = i * 1024 + tid * 4;
        const float4 kv = *(const float4*)(kg + gbase + e);
        half4 hk;
        hk[0] = (_Float16)kv.x; hk[1] = (_Float16)kv.y;
        hk[2] = (_Float16)kv.z; hk[3] = (_Float16)kv.w;
        *(half4*)(kh + gbase + e) = hk;
    }
#pragma unroll
    for (int i = 0; i < 8; ++i) {
        const int e = i * 1024 + tid * 4;
        const int s = e >> 6, d0 = e & 63;
        const float4 vv = *(const float4*)(vg + gbase + e);
        const int sp = (s & ~12) | ((s & 4) << 1) | ((s & 8) >> 1);  // b2<->b3
        Ls[(d0 + 0) * 132 + sp] = (_Float16)vv.x;
        Ls[(d0 + 1) * 132 + sp] = (_Float16)vv.y;
        Ls[(d0 + 2) * 132 + sp] = (_Float16)vv.z;
        Ls[(d0 + 3) * 132 + sp] = (_Float16)vv.w;
    }
    __syncthreads();
    const int w = tid >> 6, L = tid & 63;
    const int dr = L >> 4;
    const int c  = L & 15;
#pragma unroll
    for (int k = 0; k < 4; ++k) {
        const int d = w * 16 + k * 4 + dr;
        const half4 lo = *(const half4*)&Ls[d * 132 + c * 8];
        const half4 hi = *(const half4*)&Ls[d * 132 + c * 8 + 4];
        half8 o;
        o[0] = lo[0]; o[1] = lo[1]; o[2] = lo[2]; o[3] = lo[3];
        o[4] = hi[0]; o[5] = hi[1]; o[6] = hi[2]; o[7] = hi[3];
        *(half8*)(vt + ((size_t)(bh * D_DIM + d)) * S_LEN + sbase + c * 8) = o;
    }
}

// ---- main flash kernel: 4 waves x 64 q = 256 q per block; K-tiles of 64
__global__ __launch_bounds__(256, 2) void fa_kernel(
    const float* __restrict__ qg, const _Float16* __restrict__ kh,
    const _Float16* __restrict__ vt, float* __restrict__ outg)
{
    // Static double buffers. [row][phys 16B chunk], phys = logical ^ (row&7).
    __shared__ _Float16 Kl0[64 * 64];   // [key][d]
    __shared__ _Float16 Kl1[64 * 64];
    __shared__ _Float16 Vl0[64 * 64];   // [d][pos]  (pos = permuted key)
    __shared__ _Float16 Vl1[64 * 64];

    const int tid = threadIdx.x;
    const int w = tid >> 6;            // wave 0..3
    const int L = tid & 63;
    const int lq = L & 31;
    const int h = L >> 5;

    // 512 blocks; XCD ~ id&7 -> bh 8c..8c+7 on XCD c (4MB f16 KV fits L2)
    const int id = blockIdx.x;
    const int bh   = ((id & 7) << 3) | (id >> 6);
    const int qblk = (id >> 3) & 7;    // 8 q-blocks of 256 q
    const int qrowA = qblk * 256 + w * 32 + lq;

    // Q fragments (B operand of S^T): B[k=d][n=q], k = 16*ks + 8*h + j
    half8 qbA[4], qbB[4];
    {
        const float* qpA = qg + ((size_t)bh * S_LEN + qrowA) * D_DIM + h * 8;
        const float* qpB = qpA + 128 * D_DIM;
#pragma unroll
        for (int ks = 0; ks < 4; ++ks) {
            const float4 a0 = *(const float4*)(qpA + ks * 16);
            const float4 b0 = *(const float4*)(qpA + ks * 16 + 4);
            const float4 a1 = *(const float4*)(qpB + ks * 16);
            const float4 b1 = *(const float4*)(qpB + ks * 16 + 4);
            qbA[ks][0] = (_Float16)(a0.x * QSCALE);
            qbA[ks][1] = (_Float16)(a0.y * QSCALE);
            qbA[ks][2] = (_Float16)(a0.z * QSCALE);
            qbA[ks][3] = (_Float16)(a0.w * QSCALE);
            qbA[ks][4] = (_Float16)(b0.x * QSCALE);
            qbA[ks][5] = (_Float16)(b0.y * QSCALE);
            qbA[ks][6] = (_Float16)(b0.z * QSCALE);
            qbA[ks][7] = (_Float16)(b0.w * QSCALE);
            qbB[ks][0] = (_Float16)(a1.x * QSCALE);
            qbB[ks][1] = (_Float16)(a1.y * QSCALE);
            qbB[ks][2] = (_Float16)(a1.z * QSCALE);
            qbB[ks][3] = (_Float16)(a1.w * QSCALE);
            qbB[ks][4] = (_Float16)(b1.x * QSCALE);
            qbB[ks][5] = (_Float16)(b1.y * QSCALE);
            qbB[ks][6] = (_Float16)(b1.z * QSCALE);
            qbB[ks][7] = (_Float16)(b1.w * QSCALE);
        }
    }

    floatx16 o0A, o1A, lacA, o0B, o1B, lacB;
#pragma unroll
    for (int r = 0; r < 16; ++r) {
        o0A[r] = 0.f; o1A[r] = 0.f; lacA[r] = 0.f;
        o0B[r] = 0.f; o1B[r] = 0.f; lacB[r] = 0.f;
    }

    half8 ones;
#pragma unroll
    for (int j = 0; j < 8; ++j) ones[j] = (_Float16)1.0f;

    // staging: wave w covers rows [w*16, w*16+16), 2 GLL16 each for K and V.
    const int rloc = L >> 3, lc = L & 7;
    const int crd = lc ^ rloc;
    const _Float16* kgl = kh + (size_t)bh * S_LEN * D_DIM
                        + (size_t)(w * 16 + rloc) * D_DIM + crd * 8;
    const _Float16* vgl = vt + (size_t)bh * D_DIM * S_LEN
                        + (size_t)(w * 16 + rloc) * S_LEN + crd * 8;
    const int woff = w * 16 * 64;

#define STAGE(KD, VD) do {                                                 \
        GLL16(kgl,                     &KD[woff]);                         \
        GLL16(kgl + (size_t)8 * D_DIM, &KD[woff + 8 * 64]);                \
        GLL16(vgl,                     &VD[woff]);                         \
        GLL16(vgl + (size_t)8 * S_LEN, &VD[woff + 8 * 64]);                \
        kgl += 64 * D_DIM;                                                 \
        vgl += 64;                                                         \
    } while (0)

    // one af fragment from 8 consecutive s-values: 8 exp2 + 4 cvt_pkrtz.
    // s-regs release monotonically; no pk arrays, no pointer-to-local.
#define EXPFRAG(dst, sv, base) do {                                        \
        uint4v _u;                                                         \
        _u[0] = __builtin_bit_cast(unsigned int, __builtin_amdgcn_cvt_pkrtz( \
            __builtin_amdgcn_exp2f(sv[(base) + 0]),                        \
            __builtin_amdgcn_exp2f(sv[(base) + 1])));                      \
        _u[1] = __builtin_bit_cast(unsigned int, __builtin_amdgcn_cvt_pkrtz( \
            __builtin_amdgcn_exp2f(sv[(base) + 2]),                        \
            __builtin_amdgcn_exp2f(sv[(base) + 3])));                      \
        _u[2] = __builtin_bit_cast(unsigned int, __builtin_amdgcn_cvt_pkrtz( \
            __builtin_amdgcn_exp2f(sv[(base) + 4]),                        \
            __builtin_amdgcn_exp2f(sv[(base) + 5])));                      \
        _u[3] = __builtin_bit_cast(unsigned int, __builtin_amdgcn_cvt_pkrtz( \
            __builtin_amdgcn_exp2f(sv[(base) + 6]),                        \
            __builtin_amdgcn_exp2f(sv[(base) + 7])));                      \
        dst = __builtin_bit_cast(half8, _u);                               \
    } while (0)

#define COMPUTE(KB, VB) do {                                               \
        /* Phase 1: S^T = K Q^T merged (ka transient per ks, R9 order) */  \
        floatx16 s0A, s1A, s0B, s1B;                                       \
        _Pragma("unroll")                                                  \
        for (int r = 0; r < 16; ++r) {                                     \
            s0A[r] = 0.f; s1A[r] = 0.f; s0B[r] = 0.f; s1B[r] = 0.f;        \
        }                                                                  \
        __builtin_amdgcn_s_setprio(1);                                     \
        _Pragma("unroll")                                                  \
        for (int ks = 0; ks < 4; ++ks) {                                   \
            const int sw = (((2 * ks + h) ^ (lq & 7)) << 3);               \
            const half8 ka0 = *(const half8*)&KB[lq * 64 + sw];            \
            const half8 ka1 = *(const half8*)&KB[(32 + lq) * 64 + sw];     \
            s0A = MFMA32(ka0, qbA[ks], s0A);                               \
            s1A = MFMA32(ka1, qbA[ks], s1A);                               \
            s0B = MFMA32(ka0, qbB[ks], s0B);                               \
            s1B = MFMA32(ka1, qbB[ks], s1B);                               \
        }                                                                  \
        __builtin_amdgcn_s_setprio(0);                                     \
        /* Phase 2: exp-A frags; V loads slotted after s0A dies */         \
        half8 afA00, afA01, afA10, afA11;                                  \
        EXPFRAG(afA00, s0A, 0);                                            \
        EXPFRAG(afA01, s0A, 8);   /* s0A dead */                           \
        half8 vb0_, vb1_, vb2_, vb3_, vb4_, vb5_, vb6_, vb7_;              \
        {                                                                  \
            const int sw0 = (((0 + h) ^ (lq & 7)) << 3);                   \
            const int sw1 = (((2 + h) ^ (lq & 7)) << 3);                   \
            const int sw2 = (((4 + h) ^ (lq & 7)) << 3);                   \
            const int sw3 = (((6 + h) ^ (lq & 7)) << 3);                   \
            vb0_ = *(const half8*)&VB[lq * 64 + sw0];                      \
            vb1_ = *(const half8*)&VB[(32 + lq) * 64 + sw0];               \
            vb2_ = *(const half8*)&VB[lq * 64 + sw1];                      \
            vb3_ = *(const half8*)&VB[(32 + lq) * 64 + sw1];               \
            vb4_ = *(const half8*)&VB[lq * 64 + sw2];                      \
            vb5_ = *(const half8*)&VB[(32 + lq) * 64 + sw2];               \
            vb6_ = *(const half8*)&VB[lq * 64 + sw3];                      \
            vb7_ = *(const half8*)&VB[(32 + lq) * 64 + sw3];               \
        }                                                                  \
        EXPFRAG(afA10, s1A, 0);                                            \
        EXPFRAG(afA11, s1A, 8);   /* s1A dead; vb latency hidden */        \
        /* Phase 3: PV-A MFMAs with exp-B frags threaded between */        \
        half8 afB00, afB01, afB10, afB11;                                  \
        lacA = MFMA32(afA00 + afA01, ones, lacA);                          \
        EXPFRAG(afB00, s0B, 0);                                            \
        o0A = MFMA32(afA00, vb0_, o0A);                                    \
        EXPFRAG(afB01, s0B, 8);   /* s0B dead */                           \
        o1A = MFMA32(afA00, vb1_, o1A);                                    \
        EXPFRAG(afB10, s1B, 0);                                            \
        o0A = MFMA32(afA01, vb2_, o0A);                                    \
        EXPFRAG(afB11, s1B, 8);   /* s1B dead */                           \
        o1A = MFMA32(afA01, vb3_, o1A);                                    \
        lacA = MFMA32(afA10 + afA11, ones, lacA);                          \
        o0A = MFMA32(afA10, vb4_, o0A);                                    \
        o1A = MFMA32(afA10, vb5_, o1A);                                    \
        o0A = MFMA32(afA11, vb6_, o0A);                                    \
        o1A = MFMA32(afA11, vb7_, o1A);                                    \
        /* Phase 4: PV-B (held vb; pure MFMA) */                           \
        __builtin_amdgcn_s_setprio(1);                                     \
        lacB = MFMA32(afB00 + afB01, ones, lacB);                          \
        o0B = MFMA32(afB00, vb0_, o0B);                                    \
        o1B = MFMA32(afB00, vb1_, o1B);                                    \
        o0B = MFMA32(afB01, vb2_, o0B);                                    \
        o1B = MFMA32(afB01, vb3_, o1B);                                    \
        lacB = MFMA32(afB10 + afB11, ones, lacB);                          \
        o0B = MFMA32(afB10, vb4_, o0B);                                    \
        o1B = MFMA32(afB10, vb5_, o1B);                                    \
        o0B = MFMA32(afB11, vb6_, o0B);                                    \
        o1B = MFMA32(afB11, vb7_, o1B);                                    \
        __builtin_amdgcn_s_setprio(0);                                     \
    } while (0)

    // ---- prologue: stage tile 0 into buffer 0, drain ----
    STAGE(Kl0, Vl0);
    __syncthreads();   // tile 0 staged (implicit vmcnt(0) before s_barrier)

    // ---- main loop: 2 tiles/iter, static ping-pong, 1 barrier/tile ----
    for (int it = 0; it < 15; ++it) {
        STAGE(Kl1, Vl1);        // tile 2it+1
        COMPUTE(Kl0, Vl0);      // tile 2it
        __syncthreads();
        STAGE(Kl0, Vl0);        // tile 2it+2
        COMPUTE(Kl1, Vl1);      // tile 2it+1
        __syncthreads();
    }
    // tiles 0..29 computed; tile 30 staged in buf0
    STAGE(Kl1, Vl1);            // tile 31
    COMPUTE(Kl0, Vl0);          // tile 30
    __syncthreads();
    COMPUTE(Kl1, Vl1);          // tile 31 (no prefetch)

#undef STAGE
#undef COMPUTE
#undef EXPFRAG

    // ---- epilogue: rows of o/lac coincide -> no cross-lane needed ----
    float* obA = outg + ((size_t)bh * S_LEN + qblk * 256 + w * 32) * D_DIM;
    float* obB = obA + (size_t)128 * D_DIM;
#pragma unroll
    for (int reg = 0; reg < 16; ++reg) {
        const int q = (reg & 3) + 8 * (reg >> 2) + 4 * h;
        const float invA = 1.0f / lacA[reg];
        const float invB = 1.0f / lacB[reg];
        obA[(size_t)q * D_DIM + lq]      = o0A[reg] * invA;
        obA[(size_t)q * D_DIM + 32 + lq] = o1A[reg] * invA;
        obB[(size_t)q * D_DIM + lq]      = o0B[reg] * invB;
        obB[(size_t)q * D_DIM + 32 + lq] = o1B[reg] * invB;
    }
}

extern "C" void kernel_launch(void* const* d_in, const int* in_sizes, int n_in,
                              void* d_out, int out_size, void* d_ws, size_t ws_size,
                              hipStream_t stream) {
    const float* q = (const float*)d_in[0];
    const float* k = (const float*)d_in[1];
    const float* v = (const float*)d_in[2];
    float* out = (float*)d_out;
    (void)in_sizes; (void)n_in; (void)out_size; (void)ws_size;

    _Float16* kh = (_Float16*)d_ws;                       // 16.78 MB
    _Float16* vt = kh + (size_t)N_BH * S_LEN * D_DIM;     // 16.78 MB

    prep_kernel<<<dim3(S_LEN / 128, N_BH), dim3(256), 0, stream>>>(k, v, kh, vt);
    fa_kernel<<<dim3(512), dim3(256), 0, stream>>>(q, kh, vt, out);
}

// Round 8
// 203.773 us; speedup vs baseline: 1.0045x; 1.0045x over previous
//
#include <hip/hip_runtime.h>

// Scaled dot-product attention, B=4 H=16 S=2048 D=64, fp32 in/out.
// R14: decorrelation via launch geometry. R13's manual exp/PV interleave
// spilled mildly (FETCH+2.3MB WRITE+4.6MB, 87->92us) -- within-wave
// source-order overlap is exhausted (2 tries, 2 fails). R12 counters say
// both pipes idle >55% of every tile even with 2 waves/SIMD: the per-tile
// barrier phase-locks all 4 waves of a block (QK/exp/PV aligned), so
// nothing feeds the matrix pipe during the exp phase. Fix: 2-wave blocks,
// 1024 blocks = 4 INDEPENDENT blocks/CU (same 8 waves/CU, LDS 4x32KB=128
// <=160KB). Waves on a SIMD now come from different barrier groups and
// can anti-phase. COMPUTE reverted to R12's exact (proven, no-spill)
// schedule w/ setprio. Staging: each wave stages 32 rows (8 GLL16/tile).
// prep unchanged.

#define S_LEN 2048
#define D_DIM 64
#define N_BH  64
#define QSCALE 0.18033688011112042f  // (1/sqrt(64)) * log2(e)

typedef _Float16 half8 __attribute__((ext_vector_type(8)));
typedef _Float16 half4 __attribute__((ext_vector_type(4)));
typedef float floatx16 __attribute__((ext_vector_type(16)));
typedef unsigned int uint4v __attribute__((ext_vector_type(4)));

#define MFMA32(a, b, c) __builtin_amdgcn_mfma_f32_32x32x16_f16((a), (b), (c), 0, 0, 0)

#define GLL16(g, l) __builtin_amdgcn_global_load_lds(                      \
    (const __attribute__((address_space(1))) void*)(g),                    \
    (__attribute__((address_space(3))) void*)(l), 16, 0, 0)

// ---- pre-pass: K fp32 -> f16 (same layout, streaming); V fp32 -> f16
// transposed to [bh][d][s'] where s' = s with bits 2<->3 swapped.
__global__ __launch_bounds__(256) void prep_kernel(
    const float* __restrict__ kg, const float* __restrict__ vg,
    _Float16* __restrict__ kh, _Float16* __restrict__ vt)
{
    __shared__ _Float16 Ls[64 * 132];
    const int tid = threadIdx.x;
    const int bh = blockIdx.y;
    const int sbase = blockIdx.x * 128;
    const size_t gbase = ((size_t)(bh * S_LEN + sbase)) * D_DIM;  // 8192 floats

#pragma unroll
    for (int i = 0; i < 8; ++i) {
        const int e = i * 1024 + tid * 4;
        const float4 kv = *(const float4*)(kg + gbase + e);
        half4 hk;
        hk[0] = (_Float16)kv.x; hk[1] = (_Float16)kv.y;
        hk[2] = (_Float16)kv.z; hk[3] = (_Float16)kv.w;
        *(half4*)(kh + gbase + e) = hk;
    }
#pragma unroll
    for (int i = 0; i < 8; ++i) {
        const int e = i * 1024 + tid * 4;
        const int s = e >> 6, d0 = e & 63;
        const float4 vv = *(const float4*)(vg + gbase + e);
        const int sp = (s & ~12) | ((s & 4) << 1) | ((s & 8) >> 1);  // b2<->b3
        Ls[(d0 + 0) * 132 + sp] = (_Float16)vv.x;
        Ls[(d0 + 1) * 132 + sp] = (_Float16)vv.y;
        Ls[(d0 + 2) * 132 + sp] = (_Float16)vv.z;
        Ls[(d0 + 3) * 132 + sp] = (_Float16)vv.w;
    }
    __syncthreads();
    const int w = tid >> 6, L = tid & 63;
    const int dr = L >> 4;
    const int c  = L & 15;
#pragma unroll
    for (int k = 0; k < 4; ++k) {
        const int d = w * 16 + k * 4 + dr;
        const half4 lo = *(const half4*)&Ls[d * 132 + c * 8];
        const half4 hi = *(const half4*)&Ls[d * 132 + c * 8 + 4];
        half8 o;
        o[0] = lo[0]; o[1] = lo[1]; o[2] = lo[2]; o[3] = lo[3];
        o[4] = hi[0]; o[5] = hi[1]; o[6] = hi[2]; o[7] = hi[3];
        *(half8*)(vt + ((size_t)(bh * D_DIM + d)) * S_LEN + sbase + c * 8) = o;
    }
}

// ---- main flash kernel: 2 waves x 64 q = 128 q per block; K-tiles of 64
__global__ __launch_bounds__(128, 2) void fa_kernel(
    const float* __restrict__ qg, const _Float16* __restrict__ kh,
    const _Float16* __restrict__ vt, float* __restrict__ outg)
{
    // Static double buffers. [row][phys 16B chunk], phys = logical ^ (row&7).
    __shared__ _Float16 Kl0[64 * 64];   // [key][d]
    __shared__ _Float16 Kl1[64 * 64];
    __shared__ _Float16 Vl0[64 * 64];   // [d][pos]  (pos = permuted key)
    __shared__ _Float16 Vl1[64 * 64];

    const int tid = threadIdx.x;
    const int w = tid >> 6;            // wave 0..1
    const int L = tid & 63;
    const int lq = L & 31;
    const int h = L >> 5;

    // 1024 blocks; XCD ~ id&7 -> bh 8c..8c+7 on XCD c (4MB f16 KV fits L2)
    const int id = blockIdx.x;
    const int bh   = ((id & 7) << 3) | ((id >> 3) & 7);
    const int qblk = id >> 6;          // 16 q-blocks of 128 q
    // wave w: group A rows [qblk*128 + w*32, +32), group B = A + 64
    const int qrowA = qblk * 128 + w * 32 + lq;

    // Q fragments (B operand of S^T): B[k=d][n=q], k = 16*ks + 8*h + j
    half8 qbA[4], qbB[4];
    {
        const float* qpA = qg + ((size_t)bh * S_LEN + qrowA) * D_DIM + h * 8;
        const float* qpB = qpA + 64 * D_DIM;
#pragma unroll
        for (int ks = 0; ks < 4; ++ks) {
            const float4 a0 = *(const float4*)(qpA + ks * 16);
            const float4 b0 = *(const float4*)(qpA + ks * 16 + 4);
            const float4 a1 = *(const float4*)(qpB + ks * 16);
            const float4 b1 = *(const float4*)(qpB + ks * 16 + 4);
            qbA[ks][0] = (_Float16)(a0.x * QSCALE);
            qbA[ks][1] = (_Float16)(a0.y * QSCALE);
            qbA[ks][2] = (_Float16)(a0.z * QSCALE);
            qbA[ks][3] = (_Float16)(a0.w * QSCALE);
            qbA[ks][4] = (_Float16)(b0.x * QSCALE);
            qbA[ks][5] = (_Float16)(b0.y * QSCALE);
            qbA[ks][6] = (_Float16)(b0.z * QSCALE);
            qbA[ks][7] = (_Float16)(b0.w * QSCALE);
            qbB[ks][0] = (_Float16)(a1.x * QSCALE);
            qbB[ks][1] = (_Float16)(a1.y * QSCALE);
            qbB[ks][2] = (_Float16)(a1.z * QSCALE);
            qbB[ks][3] = (_Float16)(a1.w * QSCALE);
            qbB[ks][4] = (_Float16)(b1.x * QSCALE);
            qbB[ks][5] = (_Float16)(b1.y * QSCALE);
            qbB[ks][6] = (_Float16)(b1.z * QSCALE);
            qbB[ks][7] = (_Float16)(b1.w * QSCALE);
        }
    }

    floatx16 o0A, o1A, lacA, o0B, o1B, lacB;
#pragma unroll
    for (int r = 0; r < 16; ++r) {
        o0A[r] = 0.f; o1A[r] = 0.f; lacA[r] = 0.f;
        o0B[r] = 0.f; o1B[r] = 0.f; lacB[r] = 0.f;
    }

    half8 ones;
#pragma unroll
    for (int j = 0; j < 8; ++j) ones[j] = (_Float16)1.0f;

    // staging: wave w covers rows [w*32, w*32+32), 4 GLL16 each for K and V.
    // logical chunk = (L&7) ^ (row&7); (w*32+i*8)&7 == 0 -> lane-const perm.
    const int rloc = L >> 3, lc = L & 7;
    const int crd = lc ^ rloc;
    const _Float16* kgl = kh + (size_t)bh * S_LEN * D_DIM
                        + (size_t)(w * 32 + rloc) * D_DIM + crd * 8;
    const _Float16* vgl = vt + (size_t)bh * D_DIM * S_LEN
                        + (size_t)(w * 32 + rloc) * S_LEN + crd * 8;
    const int woff = w * 32 * 64;

#define STAGE(KD, VD) do {                                                 \
        GLL16(kgl,                      &KD[woff]);                        \
        GLL16(kgl + (size_t) 8 * D_DIM, &KD[woff +  8 * 64]);              \
        GLL16(kgl + (size_t)16 * D_DIM, &KD[woff + 16 * 64]);              \
        GLL16(kgl + (size_t)24 * D_DIM, &KD[woff + 24 * 64]);              \
        GLL16(vgl,                      &VD[woff]);                        \
        GLL16(vgl + (size_t) 8 * S_LEN, &VD[woff +  8 * 64]);              \
        GLL16(vgl + (size_t)16 * S_LEN, &VD[woff + 16 * 64]);              \
        GLL16(vgl + (size_t)24 * S_LEN, &VD[woff + 24 * 64]);              \
        kgl += 64 * D_DIM;                                                 \
        vgl += 64;                                                         \
    } while (0)

#define COMPUTE(KB, VB) do {                                               \
        /* S^T = K Q^T for both q-groups; K fragments read ONCE */         \
        floatx16 s0A, s1A, s0B, s1B;                                       \
        _Pragma("unroll")                                                  \
        for (int r = 0; r < 16; ++r) {                                     \
            s0A[r] = 0.f; s1A[r] = 0.f; s0B[r] = 0.f; s1B[r] = 0.f;        \
        }                                                                  \
        __builtin_amdgcn_s_setprio(1);                                     \
        _Pragma("unroll")                                                  \
        for (int ks = 0; ks < 4; ++ks) {                                   \
            const int sw = (((2 * ks + h) ^ (lq & 7)) << 3);               \
            const half8 ka0 = *(const half8*)&KB[lq * 64 + sw];            \
            const half8 ka1 = *(const half8*)&KB[(32 + lq) * 64 + sw];     \
            s0A = MFMA32(ka0, qbA[ks], s0A);                               \
            s1A = MFMA32(ka1, qbA[ks], s1A);                               \
            s0B = MFMA32(ka0, qbB[ks], s0B);                               \
            s1B = MFMA32(ka1, qbB[ks], s1B);                               \
        }                                                                  \
        __builtin_amdgcn_s_setprio(0);                                     \
        /* P = exp2(S^T); pk regs ARE the A-fragments */                   \
        unsigned int pkA0[8], pkA1[8], pkB0[8], pkB1[8];                   \
        _Pragma("unroll")                                                  \
        for (int p = 0; p < 8; ++p) {                                      \
            const auto eA0 = __builtin_amdgcn_cvt_pkrtz(                   \
                __builtin_amdgcn_exp2f(s0A[2 * p]),                        \
                __builtin_amdgcn_exp2f(s0A[2 * p + 1]));                   \
            const auto eA1 = __builtin_amdgcn_cvt_pkrtz(                   \
                __builtin_amdgcn_exp2f(s1A[2 * p]),                        \
                __builtin_amdgcn_exp2f(s1A[2 * p + 1]));                   \
            pkA0[p] = __builtin_bit_cast(unsigned int, eA0);               \
            pkA1[p] = __builtin_bit_cast(unsigned int, eA1);               \
        }                                                                  \
        _Pragma("unroll")                                                  \
        for (int p = 0; p < 8; ++p) {                                      \
            const auto eB0 = __builtin_amdgcn_cvt_pkrtz(                   \
                __builtin_amdgcn_exp2f(s0B[2 * p]),                        \
                __builtin_amdgcn_exp2f(s0B[2 * p + 1]));                   \
            const auto eB1 = __builtin_amdgcn_cvt_pkrtz(                   \
                __builtin_amdgcn_exp2f(s1B[2 * p]),                        \
                __builtin_amdgcn_exp2f(s1B[2 * p + 1]));                   \
            pkB0[p] = __builtin_bit_cast(unsigned int, eB0);               \
            pkB1[p] = __builtin_bit_cast(unsigned int, eB1);               \
        }                                                                  \
        /* O += P V ; lac += (af0+af1) * ones; V fragments read ONCE */    \
        __builtin_amdgcn_s_setprio(1);                                     \
        _Pragma("unroll")                                                  \
        for (int mt = 0; mt < 2; ++mt) {                                   \
            const unsigned int* pA = mt ? pkA1 : pkA0;                     \
            const unsigned int* pB = mt ? pkB1 : pkB0;                     \
            const uint4v uA0 = {pA[0], pA[1], pA[2], pA[3]};               \
            const uint4v uA1 = {pA[4], pA[5], pA[6], pA[7]};               \
            const uint4v uB0 = {pB[0], pB[1], pB[2], pB[3]};               \
            const uint4v uB1 = {pB[4], pB[5], pB[6], pB[7]};               \
            const half8 afA0 = __builtin_bit_cast(half8, uA0);             \
            const half8 afA1 = __builtin_bit_cast(half8, uA1);             \
            const half8 afB0 = __builtin_bit_cast(half8, uB0);             \
            const half8 afB1 = __builtin_bit_cast(half8, uB1);             \
            lacA = MFMA32(afA0 + afA1, ones, lacA);                        \
            lacB = MFMA32(afB0 + afB1, ones, lacB);                        \
            _Pragma("unroll")                                              \
            for (int kl = 0; kl < 2; ++kl) {                               \
                const int ksg = mt * 2 + kl;                               \
                const int sw = (((2 * ksg + h) ^ (lq & 7)) << 3);          \
                const half8 vb0 = *(const half8*)&VB[lq * 64 + sw];        \
                const half8 vb1 = *(const half8*)&VB[(32 + lq) * 64 + sw]; \
                const half8 afA = kl ? afA1 : afA0;                        \
                const half8 afB = kl ? afB1 : afB0;                        \
                o0A = MFMA32(afA, vb0, o0A);                               \
                o1A = MFMA32(afA, vb1, o1A);                               \
                o0B = MFMA32(afB, vb0, o0B);                               \
                o1B = MFMA32(afB, vb1, o1B);                               \
            }                                                              \
        }                                                                  \
        __builtin_amdgcn_s_setprio(0);                                     \
    } while (0)

    // ---- prologue: stage tile 0 into buffer 0, drain ----
    STAGE(Kl0, Vl0);
    __syncthreads();   // tile 0 staged (implicit vmcnt(0) before s_barrier)

    // ---- main loop: 2 tiles/iter, static ping-pong, 1 barrier/tile ----
    for (int it = 0; it < 15; ++it) {
        STAGE(Kl1, Vl1);        // tile 2it+1
        COMPUTE(Kl0, Vl0);      // tile 2it
        __syncthreads();
        STAGE(Kl0, Vl0);        // tile 2it+2
        COMPUTE(Kl1, Vl1);      // tile 2it+1
        __syncthreads();
    }
    // tiles 0..29 computed; tile 30 staged in buf0
    STAGE(Kl1, Vl1);            // tile 31
    COMPUTE(Kl0, Vl0);          // tile 30
    __syncthreads();
    COMPUTE(Kl1, Vl1);          // tile 31 (no prefetch)

#undef STAGE
#undef COMPUTE

    // ---- epilogue: rows of o/lac coincide -> no cross-lane needed ----
    float* obA = outg + ((size_t)bh * S_LEN + qblk * 128 + w * 32) * D_DIM;
    float* obB = obA + (size_t)64 * D_DIM;
#pragma unroll
    for (int reg = 0; reg < 16; ++reg) {
        const int q = (reg & 3) + 8 * (reg >> 2) + 4 * h;
        const float invA = 1.0f / lacA[reg];
        const float invB = 1.0f / lacB[reg];
        obA[(size_t)q * D_DIM + lq]      = o0A[reg] * invA;
        obA[(size_t)q * D_DIM + 32 + lq] = o1A[reg] * invA;
        obB[(size_t)q * D_DIM + lq]      = o0B[reg] * invB;
        obB[(size_t)q * D_DIM + 32 + lq] = o1B[reg] * invB;
    }
}

extern "C" void kernel_launch(void* const* d_in, const int* in_sizes, int n_in,
                              void* d_out, int out_size, void* d_ws, size_t ws_size,
                              hipStream_t stream) {
    const float* q = (const float*)d_in[0];
    const float* k = (const float*)d_in[1];
    const float* v = (const float*)d_in[2];
    float* out = (float*)d_out;
    (void)in_sizes; (void)n_in; (void)out_size; (void)ws_size;

    _Float16* kh = (_Float16*)d_ws;                       // 16.78 MB
    _Float16* vt = kh + (size_t)N_BH * S_LEN * D_DIM;     // 16.78 MB

    prep_kernel<<<dim3(S_LEN / 128, N_BH), dim3(256), 0, stream>>>(k, v, kh, vt);
    fa_kernel<<<dim3(1024), dim3(128), 0, stream>>>(q, kh, vt, out);
}

// Round 9
// 198.297 us; speedup vs baseline: 1.0323x; 1.0276x over previous
//
#include <hip/hip_runtime.h>

// Scaled dot-product attention, B=4 H=16 S=2048 D=64, fp32 in/out.
// R15: exp-B threaded under PV-A -- third attempt, register-ledger-driven.
// R11 spilled (vb hoisted before exp-A: vb32+s64 live = >256 unified regs).
// R13 spilled (vb hoisted mid-exp-A, held through exp-B: ~270 peak).
// R15 ledger: vb arrives only as s-regs die (1:1 trade) -- exp-A phase
// ~208 unified, PV-A||exp-B phase ~204, both < 256. Geometry reverted to
// R12's proven 4x64q/grid-512 (R14's 2-wave blocks: 92.4us, phase-lock is
// contention-driven, block independence doesn't break it). Merged QK
// (ka transient) and 16 LDS reads/tile unchanged; math order per
// accumulator bitwise-identical to R12. Exposed VALU halves
// (chain model 3554 -> 2929 cyc/tile). Gate: FETCH/WRITE must stay 32.8MB.

#define S_LEN 2048
#define D_DIM 64
#define N_BH  64
#define QSCALE 0.18033688011112042f  // (1/sqrt(64)) * log2(e)

typedef _Float16 half8 __attribute__((ext_vector_type(8)));
typedef _Float16 half4 __attribute__((ext_vector_type(4)));
typedef float floatx16 __attribute__((ext_vector_type(16)));
typedef unsigned int uint4v __attribute__((ext_vector_type(4)));

#define MFMA32(a, b, c) __builtin_amdgcn_mfma_f32_32x32x16_f16((a), (b), (c), 0, 0, 0)

#define GLL16(g, l) __builtin_amdgcn_global_load_lds(                      \
    (const __attribute__((address_space(1))) void*)(g),                    \
    (__attribute__((address_space(3))) void*)(l), 16, 0, 0)

// ---- pre-pass: K fp32 -> f16 (same layout, streaming); V fp32 -> f16
// transposed to [bh][d][s'] where s' = s with bits 2<->3 swapped.
__global__ __launch_bounds__(256) void prep_kernel(
    const float* __restrict__ kg, const float* __restrict__ vg,
    _Float16* __restrict__ kh, _Float16* __restrict__ vt)
{
    __shared__ _Float16 Ls[64 * 132];
    const int tid = threadIdx.x;
    const int bh = blockIdx.y;
    const int sbase = blockIdx.x * 128;
    const size_t gbase = ((size_t)(bh * S_LEN + sbase)) * D_DIM;  // 8192 floats

#pragma unroll
    for (int i = 0; i < 8; ++i) {
        const int e = i * 1024 + tid * 4;
        const float4 kv = *(const float4*)(kg + gbase + e);
        half4 hk;
        hk[0] = (_Float16)kv.x; hk[1] = (_Float16)kv.y;
        hk[2] = (_Float16)kv.z; hk[3] = (_Float16)kv.w;
        *(half4*)(kh + gbase + e) = hk;
    }
#pragma unroll
    for (int i = 0; i < 8; ++i) {
        const int e = i * 1024 + tid * 4;
        const int s = e >> 6, d0 = e & 63;
        const float4 vv = *(const float4*)(vg + gbase + e);
        const int sp = (s & ~12) | ((s & 4) << 1) | ((s & 8) >> 1);  // b2<->b3
        Ls[(d0 + 0) * 132 + sp] = (_Float16)vv.x;
        Ls[(d0 + 1) * 132 + sp] = (_Float16)vv.y;
        Ls[(d0 + 2) * 132 + sp] = (_Float16)vv.z;
        Ls[(d0 + 3) * 132 + sp] = (_Float16)vv.w;
    }
    __syncthreads();
    const int w = tid >> 6, L = tid & 63;
    const int dr = L >> 4;
    const int c  = L & 15;
#pragma unroll
    for (int k = 0; k < 4; ++k) {
        const int d = w * 16 + k * 4 + dr;
        const half4 lo = *(const half4*)&Ls[d * 132 + c * 8];
        const half4 hi = *(const half4*)&Ls[d * 132 + c * 8 + 4];
        half8 o;
        o[0] = lo[0]; o[1] = lo[1]; o[2] = lo[2]; o[3] = lo[3];
        o[4] = hi[0]; o[5] = hi[1]; o[6] = hi[2]; o[7] = hi[3];
        *(half8*)(vt + ((size_t)(bh * D_DIM + d)) * S_LEN + sbase + c * 8) = o;
    }
}

// ---- main flash kernel: 4 waves x 64 q = 256 q per block; K-tiles of 64
__global__ __launch_bounds__(256, 2) void fa_kernel(
    const float* __restrict__ qg, const _Float16* __restrict__ kh,
    const _Float16* __restrict__ vt, float* __restrict__ outg)
{
    // Static double buffers. [row][phys 16B chunk], phys = logical ^ (row&7).
    __shared__ _Float16 Kl0[64 * 64];   // [key][d]
    __shared__ _Float16 Kl1[64 * 64];
    __shared__ _Float16 Vl0[64 * 64];   // [d][pos]  (pos = permuted key)
    __shared__ _Float16 Vl1[64 * 64];

    const int tid = threadIdx.x;
    const int w = tid >> 6;            // wave 0..3
    const int L = tid & 63;
    const int lq = L & 31;
    const int h = L >> 5;

    // 512 blocks; XCD ~ id&7 -> bh 8c..8c+7 on XCD c (4MB f16 KV fits L2)
    const int id = blockIdx.x;
    const int bh   = ((id & 7) << 3) | (id >> 6);
    const int qblk = (id >> 3) & 7;    // 8 q-blocks of 256 q
    const int qrowA = qblk * 256 + w * 32 + lq;

    // Q fragments (B operand of S^T): B[k=d][n=q], k = 16*ks + 8*h + j
    half8 qbA[4], qbB[4];
    {
        const float* qpA = qg + ((size_t)bh * S_LEN + qrowA) * D_DIM + h * 8;
        const float* qpB = qpA + 128 * D_DIM;
#pragma unroll
        for (int ks = 0; ks < 4; ++ks) {
            const float4 a0 = *(const float4*)(qpA + ks * 16);
            const float4 b0 = *(const float4*)(qpA + ks * 16 + 4);
            const float4 a1 = *(const float4*)(qpB + ks * 16);
            const float4 b1 = *(const float4*)(qpB + ks * 16 + 4);
            qbA[ks][0] = (_Float16)(a0.x * QSCALE);
            qbA[ks][1] = (_Float16)(a0.y * QSCALE);
            qbA[ks][2] = (_Float16)(a0.z * QSCALE);
            qbA[ks][3] = (_Float16)(a0.w * QSCALE);
            qbA[ks][4] = (_Float16)(b0.x * QSCALE);
            qbA[ks][5] = (_Float16)(b0.y * QSCALE);
            qbA[ks][6] = (_Float16)(b0.z * QSCALE);
            qbA[ks][7] = (_Float16)(b0.w * QSCALE);
            qbB[ks][0] = (_Float16)(a1.x * QSCALE);
            qbB[ks][1] = (_Float16)(a1.y * QSCALE);
            qbB[ks][2] = (_Float16)(a1.z * QSCALE);
            qbB[ks][3] = (_Float16)(a1.w * QSCALE);
            qbB[ks][4] = (_Float16)(b1.x * QSCALE);
            qbB[ks][5] = (_Float16)(b1.y * QSCALE);
            qbB[ks][6] = (_Float16)(b1.z * QSCALE);
            qbB[ks][7] = (_Float16)(b1.w * QSCALE);
        }
    }

    floatx16 o0A, o1A, lacA, o0B, o1B, lacB;
#pragma unroll
    for (int r = 0; r < 16; ++r) {
        o0A[r] = 0.f; o1A[r] = 0.f; lacA[r] = 0.f;
        o0B[r] = 0.f; o1B[r] = 0.f; lacB[r] = 0.f;
    }

    half8 ones;
#pragma unroll
    for (int j = 0; j < 8; ++j) ones[j] = (_Float16)1.0f;

    // staging: wave w covers rows [w*16, w*16+16), 2 GLL16 each for K and V.
    const int rloc = L >> 3, lc = L & 7;
    const int crd = lc ^ rloc;
    const _Float16* kgl = kh + (size_t)bh * S_LEN * D_DIM
                        + (size_t)(w * 16 + rloc) * D_DIM + crd * 8;
    const _Float16* vgl = vt + (size_t)bh * D_DIM * S_LEN
                        + (size_t)(w * 16 + rloc) * S_LEN + crd * 8;
    const int woff = w * 16 * 64;

#define STAGE(KD, VD) do {                                                 \
        GLL16(kgl,                     &KD[woff]);                         \
        GLL16(kgl + (size_t)8 * D_DIM, &KD[woff + 8 * 64]);                \
        GLL16(vgl,                     &VD[woff]);                         \
        GLL16(vgl + (size_t)8 * S_LEN, &VD[woff + 8 * 64]);                \
        kgl += 64 * D_DIM;                                                 \
        vgl += 64;                                                         \
    } while (0)

    // one af fragment from 8 consecutive s-values: 8 exp2 + 4 cvt_pkrtz.
    // s-regs release monotonically; no pk arrays, no pointer-to-local.
#define EXPFRAG(dst, sv, base) do {                                        \
        uint4v _u;                                                         \
        _u[0] = __builtin_bit_cast(unsigned int, __builtin_amdgcn_cvt_pkrtz( \
            __builtin_amdgcn_exp2f(sv[(base) + 0]),                        \
            __builtin_amdgcn_exp2f(sv[(base) + 1])));                      \
        _u[1] = __builtin_bit_cast(unsigned int, __builtin_amdgcn_cvt_pkrtz( \
            __builtin_amdgcn_exp2f(sv[(base) + 2]),                        \
            __builtin_amdgcn_exp2f(sv[(base) + 3])));                      \
        _u[2] = __builtin_bit_cast(unsigned int, __builtin_amdgcn_cvt_pkrtz( \
            __builtin_amdgcn_exp2f(sv[(base) + 4]),                        \
            __builtin_amdgcn_exp2f(sv[(base) + 5])));                      \
        _u[3] = __builtin_bit_cast(unsigned int, __builtin_amdgcn_cvt_pkrtz( \
            __builtin_amdgcn_exp2f(sv[(base) + 6]),                        \
            __builtin_amdgcn_exp2f(sv[(base) + 7])));                      \
        dst = __builtin_bit_cast(half8, _u);                               \
    } while (0)

#define COMPUTE(KB, VB) do {                                               \
        /* Phase 1: S^T = K Q^T merged (ka transient, R12-identical) */    \
        floatx16 s0A, s1A, s0B, s1B;                                       \
        _Pragma("unroll")                                                  \
        for (int r = 0; r < 16; ++r) {                                     \
            s0A[r] = 0.f; s1A[r] = 0.f; s0B[r] = 0.f; s1B[r] = 0.f;        \
        }                                                                  \
        __builtin_amdgcn_s_setprio(1);                                     \
        _Pragma("unroll")                                                  \
        for (int ks = 0; ks < 4; ++ks) {                                   \
            const int sw = (((2 * ks + h) ^ (lq & 7)) << 3);               \
            const half8 ka0 = *(const half8*)&KB[lq * 64 + sw];            \
            const half8 ka1 = *(const half8*)&KB[(32 + lq) * 64 + sw];     \
            s0A = MFMA32(ka0, qbA[ks], s0A);                               \
            s1A = MFMA32(ka1, qbA[ks], s1A);                               \
            s0B = MFMA32(ka0, qbB[ks], s0B);                               \
            s1B = MFMA32(ka1, qbB[ks], s1B);                               \
        }                                                                  \
        __builtin_amdgcn_s_setprio(0);                                     \
        const int sw0 = ((h       ^ (lq & 7)) << 3);                       \
        const int sw1 = (((2 + h) ^ (lq & 7)) << 3);                       \
        const int sw2 = (((4 + h) ^ (lq & 7)) << 3);                       \
        const int sw3 = (((6 + h) ^ (lq & 7)) << 3);                       \
        /* Phase 2: exp-A; vb0-3 loads threaded (arrive as s-A dies) */    \
        half8 afA00, afA01, afA10, afA11;                                  \
        half8 vb0_, vb1_, vb2_, vb3_;                                      \
        EXPFRAG(afA00, s0A, 0);                                            \
        vb0_ = *(const half8*)&VB[lq * 64 + sw0];                          \
        vb1_ = *(const half8*)&VB[(32 + lq) * 64 + sw0];                   \
        EXPFRAG(afA01, s0A, 8);   /* s0A dead */                           \
        vb2_ = *(const half8*)&VB[lq * 64 + sw1];                          \
        vb3_ = *(const half8*)&VB[(32 + lq) * 64 + sw1];                   \
        EXPFRAG(afA10, s1A, 0);                                            \
        EXPFRAG(afA11, s1A, 8);   /* s1A dead */                           \
        /* Phase 3: PV-A MFMAs with exp-B frags + vb4-7 loads threaded */  \
        half8 afB00, afB01, afB10, afB11;                                  \
        half8 vb4_, vb5_, vb6_, vb7_;                                      \
        lacA = MFMA32(afA00 + afA01, ones, lacA);                          \
        EXPFRAG(afB00, s0B, 0);                                            \
        o0A = MFMA32(afA00, vb0_, o0A);                                    \
        EXPFRAG(afB01, s0B, 8);   /* s0B dead */                           \
        o1A = MFMA32(afA00, vb1_, o1A);                                    \
        vb4_ = *(const half8*)&VB[lq * 64 + sw2];                          \
        vb5_ = *(const half8*)&VB[(32 + lq) * 64 + sw2];                   \
        EXPFRAG(afB10, s1B, 0);                                            \
        o0A = MFMA32(afA01, vb2_, o0A);                                    \
        EXPFRAG(afB11, s1B, 8);   /* s1B dead */                           \
        o1A = MFMA32(afA01, vb3_, o1A);                                    \
        vb6_ = *(const half8*)&VB[lq * 64 + sw3];                          \
        vb7_ = *(const half8*)&VB[(32 + lq) * 64 + sw3];                   \
        lacA = MFMA32(afA10 + afA11, ones, lacA);                          \
        o0A = MFMA32(afA10, vb4_, o0A);                                    \
        o1A = MFMA32(afA10, vb5_, o1A);                                    \
        o0A = MFMA32(afA11, vb6_, o0A);                                    \
        o1A = MFMA32(afA11, vb7_, o1A);                                    \
        /* Phase 4: PV-B (held vb; pure MFMA) */                           \
        __builtin_amdgcn_s_setprio(1);                                     \
        lacB = MFMA32(afB00 + afB01, ones, lacB);                          \
        o0B = MFMA32(afB00, vb0_, o0B);                                    \
        o1B = MFMA32(afB00, vb1_, o1B);                                    \
        o0B = MFMA32(afB01, vb2_, o0B);                                    \
        o1B = MFMA32(afB01, vb3_, o1B);                                    \
        lacB = MFMA32(afB10 + afB11, ones, lacB);                          \
        o0B = MFMA32(afB10, vb4_, o0B);                                    \
        o1B = MFMA32(afB10, vb5_, o1B);                                    \
        o0B = MFMA32(afB11, vb6_, o0B);                                    \
        o1B = MFMA32(afB11, vb7_, o1B);                                    \
        __builtin_amdgcn_s_setprio(0);                                     \
    } while (0)

    // ---- prologue: stage tile 0 into buffer 0, drain ----
    STAGE(Kl0, Vl0);
    __syncthreads();   // tile 0 staged (implicit vmcnt(0) before s_barrier)

    // ---- main loop: 2 tiles/iter, static ping-pong, 1 barrier/tile ----
    for (int it = 0; it < 15; ++it) {
        STAGE(Kl1, Vl1);        // tile 2it+1
        COMPUTE(Kl0, Vl0);      // tile 2it
        __syncthreads();
        STAGE(Kl0, Vl0);        // tile 2it+2
        COMPUTE(Kl1, Vl1);      // tile 2it+1
        __syncthreads();
    }
    // tiles 0..29 computed; tile 30 staged in buf0
    STAGE(Kl1, Vl1);            // tile 31
    COMPUTE(Kl0, Vl0);          // tile 30
    __syncthreads();
    COMPUTE(Kl1, Vl1);          // tile 31 (no prefetch)

#undef STAGE
#undef COMPUTE
#undef EXPFRAG

    // ---- epilogue: rows of o/lac coincide -> no cross-lane needed ----
    float* obA = outg + ((size_t)bh * S_LEN + qblk * 256 + w * 32) * D_DIM;
    float* obB = obA + (size_t)128 * D_DIM;
#pragma unroll
    for (int reg = 0; reg < 16; ++reg) {
        const int q = (reg & 3) + 8 * (reg >> 2) + 4 * h;
        const float invA = 1.0f / lacA[reg];
        const float invB = 1.0f / lacB[reg];
        obA[(size_t)q * D_DIM + lq]      = o0A[reg] * invA;
        obA[(size_t)q * D_DIM + 32 + lq] = o1A[reg] * invA;
        obB[(size_t)q * D_DIM + lq]      = o0B[reg] * invB;
        obB[(size_t)q * D_DIM + 32 + lq] = o1B[reg] * invB;
    }
}

extern "C" void kernel_launch(void* const* d_in, const int* in_sizes, int n_in,
                              void* d_out, int out_size, void* d_ws, size_t ws_size,
                              hipStream_t stream) {
    const float* q = (const float*)d_in[0];
    const float* k = (const float*)d_in[1];
    const float* v = (const float*)d_in[2];
    float* out = (float*)d_out;
    (void)in_sizes; (void)n_in; (void)out_size; (void)ws_size;

    _Float16* kh = (_Float16*)d_ws;                       // 16.78 MB
    _Float16* vt = kh + (size_t)N_BH * S_LEN * D_DIM;     // 16.78 MB

    prep_kernel<<<dim3(S_LEN / 128, N_BH), dim3(256), 0, stream>>>(k, v, kh, vt);
    fa_kernel<<<dim3(512), dim3(256), 0, stream>>>(q, kh, vt, out);
}